// Round 5
// baseline (1301.952 us; speedup 1.0000x reference)
//
#include <hip/hip_runtime.h>
#include <hip/hip_bf16.h>
#include <stdint.h>

// LinearMultiHeadedAttention: B=16, S=4096, D=1024, H=16, DK=64
// R5: 256x256 8-wave 4-phase GEMM with DEEP pipeline:
//     A = fp32 key/value read directly (conv fused): register ring depth-4
//     (issue t+4 at P0(t), cvt+ds_write t+1) -> ~744cy latency cover.
//     B = W bf16 via global_load_lds, TRIPLE-buffered, staged 2 tiles ahead
//     so the oldest-first vmcnt drain {A(t+1),B(t)} is exactly the needed set.
//     steady-state s_waitcnt vmcnt(32); never drains the deep prefetch.

using bf16 = __hip_bfloat16;
typedef __attribute__((ext_vector_type(8))) short short8;  // bf16x8 MFMA frag
typedef __attribute__((ext_vector_type(4))) float f32x4;

#define NB_B 16
#define SEQ 4096
#define DM 1024
#define NH 16
#define DKH 64

__device__ __forceinline__ void gload_lds16(const void* g, void* l) {
  __builtin_amdgcn_global_load_lds((const __attribute__((address_space(1))) void*)g,
                                   (__attribute__((address_space(3))) void*)l, 16, 0, 0);
}

__device__ __forceinline__ short8 pack_bf16x8(float4 a, float4 b) {
  union { bf16 h[8]; short8 v; } pk;
  pk.h[0] = __float2bfloat16(a.x); pk.h[1] = __float2bfloat16(a.y);
  pk.h[2] = __float2bfloat16(a.z); pk.h[3] = __float2bfloat16(a.w);
  pk.h[4] = __float2bfloat16(b.x); pk.h[5] = __float2bfloat16(b.y);
  pk.h[6] = __float2bfloat16(b.z); pk.h[7] = __float2bfloat16(b.w);
  return pk.v;
}

// ---------------- fp32 -> bf16 conversion (weights only) ----------------
__global__ __launch_bounds__(256) void conv_kernel(const float* __restrict__ src,
                                                   bf16* __restrict__ dst, long n4) {
  long i = (long)blockIdx.x * blockDim.x + threadIdx.x;
  const long stride = (long)gridDim.x * blockDim.x;
  for (; i < n4; i += stride) {
    float4 v = ((const float4*)src)[i];
    union { ushort4 u; bf16 h[4]; } o;
    o.h[0] = __float2bfloat16(v.x);
    o.h[1] = __float2bfloat16(v.y);
    o.h[2] = __float2bfloat16(v.z);
    o.h[3] = __float2bfloat16(v.w);
    ((ushort4*)dst)[i] = o.u;
  }
}

// ---------------- 256x256 8-wave 4-phase deep-pipelined GEMM ----------------
// C[row][col] = sum_c A[row][c] * W[col][c]  (+bias[col]); KPROJ: elu+1, Ksum.
// A: fp32 [rowsTot][DM] (key/value directly, cvt fused). W: bf16 [DM][DM].
// Out TRANSPOSED bf16 outT[col][row].
// LDS: As[2][256][64] + Bs[3][256][64] bf16 = 160 KiB.
// Swizzle byte ^= (row&7)<<4 on both (A: swizzled ds_write; B: pre-swizzled src).
template <int KPROJ>
__global__ __launch_bounds__(512, 1) void gemm256(
    const float* __restrict__ A, const bf16* __restrict__ W,
    const float* __restrict__ bias, bf16* __restrict__ outT,
    float* __restrict__ Ksum, int rowsTot, int b0, int chunk) {
  __shared__ bf16 As[2][256 * 64];
  __shared__ bf16 Bs[3][256 * 64];
  const int tid = threadIdx.x;
  const int lane = tid & 63;
  const int wid = tid >> 6;   // 0..7
  const int wr = wid >> 2;    // 0..1 -> 128-row half
  const int wc = wid & 3;     // 0..3 -> 64-col quarter
  // T1 XCD swizzle: contiguous row-tile chunk per XCD, col-tile fastest.
  const int wgid = (blockIdx.x & 7) * chunk + (blockIdx.x >> 3);
  const int row0 = (wgid >> 2) * 256;
  const int col0 = (wgid & 3) * 256;

  f32x4 acc[8][4] = {};

  const int bsrc = ((lane & 7) ^ (lane >> 3)) * 8;  // pre-swizzled B src col
  const int xr = (lane & 7) << 4;                   // read-side XOR key
  const int lr = lane & 15;
  const int lk = (lane >> 4) * 16;                  // k-slot byte offset

  // A fp32 source: thread covers rows wid*32 + j*8 + (lane>>3), cols (lane&7)*8+[0,8)
  const float* Afp = A + (long)(row0 + wid * 32 + (lane >> 3)) * DM + (lane & 7) * 8;
  // A swizzled ds_write: row&7 == lane>>3  ->  slot constant per thread
  const int awbase = (wid * 32 + (lane >> 3)) * 128 + (((lane & 7) ^ (lane >> 3)) << 4);
  // B staging source (pre-swizzled) and LDS dest base
  const bf16* Wb = W + (long)(col0 + wid * 32 + (lane >> 3)) * DM + bsrc;
  const int sdst = wid * 32 * 64;  // elems

  float4 ring[4][8];  // depth-4 A prefetch (constant-indexed under full unroll)

#define ISSUE_A(slot, kt_) \
  _Pragma("unroll") for (int j = 0; j < 4; ++j) { \
    ring[slot][2 * j]     = *(const float4*)(Afp + (long)j * 8 * DM + (kt_) * 64); \
    ring[slot][2 * j + 1] = *(const float4*)(Afp + (long)j * 8 * DM + (kt_) * 64 + 4); \
  }
#define ISSUE_B(buf, kt_) \
  _Pragma("unroll") for (int j = 0; j < 4; ++j) \
    gload_lds16(Wb + (long)j * 8 * DM + (kt_) * 64, (void*)&Bs[buf][sdst + j * 512]);
#define WRITE_A(abuf, slot) \
  _Pragma("unroll") for (int j = 0; j < 4; ++j) \
    *(short8*)((char*)As[abuf] + awbase + j * 1024) = \
        pack_bf16x8(ring[slot][2 * j], ring[slot][2 * j + 1]);

  // ---- prologue: age order must match steady state: A0 A1 B0 A2 B1 A3
  ISSUE_A(0, 0)
  ISSUE_A(1, 1)
  ISSUE_B(0, 0)
  ISSUE_A(2, 2)
  ISSUE_B(1, 1)
  ISSUE_A(3, 3)
  asm volatile("s_waitcnt vmcnt(32)" ::: "memory");  // drain A(0) only
  WRITE_A(0, 0)

  short8 af[4], bfv[4];

#pragma unroll
  for (int kt = 0; kt < 16; ++kt) {
    const char* Asc = (const char*)As[kt & 1];
    const char* Bsc = (const char*)Bs[kt % 3];

    // ---- P0 head: issue B(t+2), issue A(t+4), wait {A(t+1),B(t)}, write A(t+1)
    if (kt + 2 < 16) { ISSUE_B((kt + 2) % 3, kt + 2) }
    if (kt + 4 < 16) { ISSUE_A((kt + 4) & 3, kt + 4) }
    if (kt <= 12)      asm volatile("s_waitcnt vmcnt(32) lgkmcnt(0)" ::: "memory");
    else if (kt == 13) asm volatile("s_waitcnt vmcnt(16) lgkmcnt(0)" ::: "memory");
    else if (kt == 14) asm volatile("s_waitcnt vmcnt(4) lgkmcnt(0)" ::: "memory");
    else               asm volatile("s_waitcnt vmcnt(0) lgkmcnt(0)" ::: "memory");
    if (kt + 1 < 16) { WRITE_A((kt + 1) & 1, (kt + 1) & 3) }
    asm volatile("s_barrier" ::: "memory");

    // ---- P0: frags A m0-3 kk0 + B kk0, MFMA
#pragma unroll
    for (int m = 0; m < 4; ++m)
      af[m] = *(const short8*)(Asc + (wr * 128 + m * 16 + lr) * 128 + (lk ^ xr));
#pragma unroll
    for (int n = 0; n < 4; ++n)
      bfv[n] = *(const short8*)(Bsc + (wc * 64 + n * 16 + lr) * 128 + (lk ^ xr));
    __builtin_amdgcn_sched_barrier(0);
    __builtin_amdgcn_s_setprio(1);
#pragma unroll
    for (int m = 0; m < 4; ++m)
#pragma unroll
      for (int n = 0; n < 4; ++n)
        acc[m][n] = __builtin_amdgcn_mfma_f32_16x16x32_bf16(af[m], bfv[n], acc[m][n], 0, 0, 0);
    __builtin_amdgcn_s_setprio(0);
    asm volatile("s_barrier" ::: "memory");

    // ---- P1: frags A m4-7 kk0, MFMA
#pragma unroll
    for (int m = 0; m < 4; ++m)
      af[m] = *(const short8*)(Asc + (wr * 128 + (m + 4) * 16 + lr) * 128 + (lk ^ xr));
    asm volatile("s_barrier" ::: "memory");
    __builtin_amdgcn_sched_barrier(0);
    __builtin_amdgcn_s_setprio(1);
#pragma unroll
    for (int m = 0; m < 4; ++m)
#pragma unroll
      for (int n = 0; n < 4; ++n)
        acc[m + 4][n] = __builtin_amdgcn_mfma_f32_16x16x32_bf16(af[m], bfv[n], acc[m + 4][n], 0, 0, 0);
    __builtin_amdgcn_s_setprio(0);
    asm volatile("s_barrier" ::: "memory");

    // ---- P2: frags A m0-3 kk1 + B kk1, MFMA
#pragma unroll
    for (int m = 0; m < 4; ++m)
      af[m] = *(const short8*)(Asc + (wr * 128 + m * 16 + lr) * 128 + ((64 + lk) ^ xr));
#pragma unroll
    for (int n = 0; n < 4; ++n)
      bfv[n] = *(const short8*)(Bsc + (wc * 64 + n * 16 + lr) * 128 + ((64 + lk) ^ xr));
    asm volatile("s_barrier" ::: "memory");
    __builtin_amdgcn_sched_barrier(0);
    __builtin_amdgcn_s_setprio(1);
#pragma unroll
    for (int m = 0; m < 4; ++m)
#pragma unroll
      for (int n = 0; n < 4; ++n)
        acc[m][n] = __builtin_amdgcn_mfma_f32_16x16x32_bf16(af[m], bfv[n], acc[m][n], 0, 0, 0);
    __builtin_amdgcn_s_setprio(0);
    asm volatile("s_barrier" ::: "memory");

    // ---- P3: frags A m4-7 kk1, MFMA
#pragma unroll
    for (int m = 0; m < 4; ++m)
      af[m] = *(const short8*)(Asc + (wr * 128 + (m + 4) * 16 + lr) * 128 + ((64 + lk) ^ xr));
    asm volatile("s_barrier" ::: "memory");
    __builtin_amdgcn_sched_barrier(0);
    __builtin_amdgcn_s_setprio(1);
#pragma unroll
    for (int m = 0; m < 4; ++m)
#pragma unroll
      for (int n = 0; n < 4; ++n)
        acc[m + 4][n] = __builtin_amdgcn_mfma_f32_16x16x32_bf16(af[m], bfv[n], acc[m + 4][n], 0, 0, 0);
    __builtin_amdgcn_s_setprio(0);
    asm volatile("s_barrier" ::: "memory");
  }
#undef ISSUE_A
#undef ISSUE_B
#undef WRITE_A

  // ---- epilogue: bias (+ elu+1 + Ksum), bf16, transposed store
  const int bglob = b0 + (row0 >> 12);
#pragma unroll
  for (int n = 0; n < 4; ++n) {
    const int colg = col0 + wc * 64 + n * 16 + lr;
    const float bv = bias[colg];
    float csum = 0.f;
#pragma unroll
    for (int m = 0; m < 8; ++m) {
      const int r = row0 + wr * 128 + m * 16 + (lane >> 4) * 4;
      union { ushort4 u; bf16 h[4]; } pk;
#pragma unroll
      for (int i = 0; i < 4; ++i) {
        float v = acc[m][n][i] + bv;
        if (KPROJ) { v = v > 0.f ? v + 1.f : __expf(v); csum += v; }
        pk.h[i] = __float2bfloat16(v);
      }
      *(ushort4*)&outT[(long)colg * rowsTot + r] = pk.u;
    }
    if (KPROJ) {
      csum += __shfl_xor(csum, 16);
      csum += __shfl_xor(csum, 32);
      if (lane < 16) atomicAdd(&Ksum[(long)bglob * DM + colg], csum);
    }
  }
}

// ---------------- KV partials: KVp[sp,b,h] = K^T @ V over s-range ----------
__global__ __launch_bounds__(256) void kv_kernel(
    const bf16* __restrict__ KT, const bf16* __restrict__ VT,
    float* __restrict__ KVp, int rowsTot, int b0) {
  const int sp = blockIdx.x & 3;
  const int h = (blockIdx.x >> 2) & 15;
  const int b_loc = blockIdx.x >> 6;
  const int lane = threadIdx.x & 63;
  const int w = threadIdx.x >> 6;
  const long srow = (long)b_loc * SEQ + sp * (SEQ / 4) + ((lane >> 4) * 8);
  const bf16* Ab = KT + (long)(h * DKH + w * 16 + (lane & 15)) * rowsTot + srow;
  const bf16* Bb = VT + (long)(h * DKH + (lane & 15)) * rowsTot + srow;
  f32x4 acc[4] = {};
#pragma unroll 2
  for (int s = 0; s < SEQ / 4; s += 32) {
    short8 a = *(const short8*)(Ab + s);
#pragma unroll
    for (int n = 0; n < 4; ++n) {
      short8 bv = *(const short8*)(Bb + (long)n * 16 * rowsTot + s);
      acc[n] = __builtin_amdgcn_mfma_f32_16x16x32_bf16(a, bv, acc[n], 0, 0, 0);
    }
  }
  float* o = KVp + (((long)sp * NB_B + (b0 + b_loc)) * NH + h) * DKH * DKH;
#pragma unroll
  for (int n = 0; n < 4; ++n)
#pragma unroll
    for (int i = 0; i < 4; ++i)
      o[(w * 16 + (lane >> 4) * 4 + i) * DKH + n * 16 + (lane & 15)] = acc[n][i];
}

// ---------------- small fp32 vec-mat ----------------
template <int ELU>
__global__ __launch_bounds__(256) void vecmat_kernel(
    const float* __restrict__ in, const float* __restrict__ W,
    const float* __restrict__ bias, float* __restrict__ outp) {
  const int b = blockIdx.x >> 5;
  const int n0 = (blockIdx.x & 31) * 32;
  const int lane = threadIdx.x & 63;
  const int w = threadIdx.x >> 6;
  float4 qv[4];
#pragma unroll
  for (int it = 0; it < 4; ++it)
    qv[it] = *(const float4*)&in[(long)b * DM + it * 256 + lane * 4];
#pragma unroll
  for (int j = 0; j < 8; ++j) {
    const int n = n0 + w * 8 + j;
    const float* wrow = W + (long)n * DM;
    float s = 0.f;
#pragma unroll
    for (int it = 0; it < 4; ++it) {
      float4 wv = *(const float4*)&wrow[it * 256 + lane * 4];
      s += qv[it].x * wv.x + qv[it].y * wv.y + qv[it].z * wv.z + qv[it].w * wv.w;
    }
    s += __shfl_xor(s, 1);  s += __shfl_xor(s, 2);  s += __shfl_xor(s, 4);
    s += __shfl_xor(s, 8);  s += __shfl_xor(s, 16); s += __shfl_xor(s, 32);
    if (lane == 0) {
      float v = s + bias[n];
      if (ELU) v = v > 0.f ? v + 1.f : __expf(v);
      outp[(long)b * DM + n] = v;
    }
  }
}

// ---- x = (Q . KV) * Z with KV = sum of 4 partials
__global__ __launch_bounds__(256) void xcomp_kernel(
    const float* __restrict__ Q, const float* __restrict__ KVp,
    const float* __restrict__ Ksum, float* __restrict__ xb) {
  const int b = blockIdx.x;
  const int t = threadIdx.x;
  const int h = t >> 4;
  const int m0 = (t & 15) * 4;
  const float* q = Q + (long)b * DM + h * DKH;
  const float* ks = Ksum + (long)b * DM + h * DKH;
  const long kvoff = ((long)b * NH + h) * DKH * DKH;
  const long spstride = (long)NB_B * NH * DKH * DKH;
  float zden = 0.f;
#pragma unroll
  for (int d = 0; d < DKH; ++d) zden += q[d] * ks[d];
  const float z = 1.f / (zden + 1e-6f);
  float nv[4] = {0.f, 0.f, 0.f, 0.f};
  for (int d = 0; d < DKH; ++d) {
    const float qd = q[d];
#pragma unroll
    for (int j = 0; j < 4; ++j) {
      const long idx = kvoff + d * DKH + m0 + j;
      nv[j] += qd * (KVp[idx] + KVp[idx + spstride] +
                     KVp[idx + 2 * spstride] + KVp[idx + 3 * spstride]);
    }
  }
  float* xo = xb + (long)b * DM + h * DKH + m0;
#pragma unroll
  for (int j = 0; j < 4; ++j) xo[j] = nv[j] * z;
}

extern "C" void kernel_launch(void* const* d_in, const int* in_sizes, int n_in,
                              void* d_out, int out_size, void* d_ws, size_t ws_size,
                              hipStream_t stream) {
  (void)in_sizes; (void)n_in; (void)out_size;
  const float* query = (const float*)d_in[0];
  const float* key   = (const float*)d_in[1];
  const float* value = (const float*)d_in[2];
  const float* Wq = (const float*)d_in[3];
  const float* bq = (const float*)d_in[4];
  const float* Wk = (const float*)d_in[5];
  const float* bk = (const float*)d_in[6];
  const float* Wv = (const float*)d_in[7];
  const float* bv = (const float*)d_in[8];
  const float* Wo = (const float*)d_in[9];
  const float* bo = (const float*)d_in[10];
  float* out = (float*)d_out;

  char* p = (char*)d_ws;
  bf16* WkB = (bf16*)p;  p += (size_t)DM * DM * 2;
  bf16* WvB = (bf16*)p;  p += (size_t)DM * DM * 2;
  float* KVp = (float*)p; p += (size_t)4 * NB_B * NH * DKH * DKH * 4;
  float* Ksum = (float*)p; p += (size_t)NB_B * DM * 4;
  float* Q = (float*)p;  p += (size_t)NB_B * DM * 4;
  float* xb = (float*)p; p += (size_t)NB_B * DM * 4;
  const size_t fixed = (size_t)(p - (char*)d_ws);
  const size_t per_b = (size_t)2 * SEQ * DM * 2;  // kT+vT per batch (bf16)
  if (ws_size < fixed + per_b) return;
  int nbc = (int)((ws_size - fixed) / per_b);
  if (nbc > NB_B) nbc = NB_B;
  bf16* kT = (bf16*)p; p += (size_t)nbc * SEQ * DM * 2;
  bf16* vT = (bf16*)p; p += (size_t)nbc * SEQ * DM * 2;

  hipMemsetAsync(Ksum, 0, (size_t)NB_B * DM * 4, stream);
  conv_kernel<<<512, 256, 0, stream>>>(Wk, WkB, (long)DM * DM / 4);
  conv_kernel<<<512, 256, 0, stream>>>(Wv, WvB, (long)DM * DM / 4);
  vecmat_kernel<1><<<NB_B * 32, 256, 0, stream>>>(query, Wq, bq, Q);

  for (int b0 = 0; b0 < NB_B; b0 += nbc) {
    const int nb = (NB_B - b0 < nbc) ? (NB_B - b0) : nbc;
    const int rows = nb * SEQ;
    const int nwg = (rows / 256) * 4;
    gemm256<1><<<nwg, 512, 0, stream>>>(key + (size_t)b0 * SEQ * DM, WkB, bk, kT, Ksum, rows, b0, nwg / 8);
    gemm256<0><<<nwg, 512, 0, stream>>>(value + (size_t)b0 * SEQ * DM, WvB, bv, vT, (float*)nullptr, rows, b0, nwg / 8);
    kv_kernel<<<nb * NH * 4, 256, 0, stream>>>(kT, vT, KVp, rows, b0);
  }

  xcomp_kernel<<<NB_B, 256, 0, stream>>>(Q, KVp, Ksum, xb);
  vecmat_kernel<0><<<NB_B * 32, 256, 0, stream>>>(xb, Wo, bo, out);
}

// Round 6
// 693.832 us; speedup vs baseline: 1.8765x; 1.8765x over previous
//
#include <hip/hip_runtime.h>
#include <hip/hip_bf16.h>
#include <stdint.h>

// LinearMultiHeadedAttention: B=16, S=4096, D=1024, H=16, DK=64
// R6: 256x256 8-wave GEMM, BK=32, TRIPLE-buffered gload_lds staging for
//     BOTH operands (A = fp32 key/value read directly, cvt at frag-read;
//     B = bf16 W). No register staging at all (R5 spilled: rule #20).
//     Stage 2 tiles ahead, 6 loads/tile, steady vmcnt(12). 3-unrolled loop
//     so every buffer index is compile-time.

using bf16 = __hip_bfloat16;
typedef __attribute__((ext_vector_type(8))) short short8;  // bf16x8 MFMA frag
typedef __attribute__((ext_vector_type(4))) float f32x4;

#define NB_B 16
#define SEQ 4096
#define DM 1024
#define NH 16
#define DKH 64

__device__ __forceinline__ void gload_lds16(const void* g, void* l) {
  __builtin_amdgcn_global_load_lds((const __attribute__((address_space(1))) void*)g,
                                   (__attribute__((address_space(3))) void*)l, 16, 0, 0);
}

__device__ __forceinline__ short8 cvt8(f32x4 a, f32x4 b) {
  union { bf16 h[8]; short8 v; } pk;
  pk.h[0] = __float2bfloat16(a[0]); pk.h[1] = __float2bfloat16(a[1]);
  pk.h[2] = __float2bfloat16(a[2]); pk.h[3] = __float2bfloat16(a[3]);
  pk.h[4] = __float2bfloat16(b[0]); pk.h[5] = __float2bfloat16(b[1]);
  pk.h[6] = __float2bfloat16(b[2]); pk.h[7] = __float2bfloat16(b[3]);
  return pk.v;
}

// ---------------- fp32 -> bf16 conversion (weights only) ----------------
__global__ __launch_bounds__(256) void conv_kernel(const float* __restrict__ src,
                                                   bf16* __restrict__ dst, long n4) {
  long i = (long)blockIdx.x * blockDim.x + threadIdx.x;
  const long stride = (long)gridDim.x * blockDim.x;
  for (; i < n4; i += stride) {
    float4 v = ((const float4*)src)[i];
    union { ushort4 u; bf16 h[4]; } o;
    o.h[0] = __float2bfloat16(v.x);
    o.h[1] = __float2bfloat16(v.y);
    o.h[2] = __float2bfloat16(v.z);
    o.h[3] = __float2bfloat16(v.w);
    ((ushort4*)dst)[i] = o.u;
  }
}

// ---------------- 256x256 8-wave BK=32 triple-buffered GEMM ----------------
// C[row][col] = sum_c A[row][c] * W[col][c]  (+bias[col]); KPROJ: elu+1, Ksum.
// A: fp32 [rowsTot][DM] (key/value directly). W: bf16 [DM][DM].
// Out TRANSPOSED bf16 outT[col][row].
// LDS: As fp32 [3][256][32] (32KB ea) + Bs bf16 [3][256][32] (16KB ea) = 144KB.
// Swizzles: A rows 128B, chunk ^= row&7; B rows 64B, chunk ^= (row>>1)&3.
template <int KPROJ>
__global__ __launch_bounds__(512, 2) void gemm256(
    const float* __restrict__ A, const bf16* __restrict__ W,
    const float* __restrict__ bias, bf16* __restrict__ outT,
    float* __restrict__ Ksum, int rowsTot, int b0, int chunk) {
  __shared__ float As[3][256 * 32];
  __shared__ bf16 Bs[3][256 * 32];
  const int tid = threadIdx.x;
  const int lane = tid & 63;
  const int wid = tid >> 6;   // 0..7
  const int wr = wid >> 2;    // 0..1 -> 128-row half
  const int wc = wid & 3;     // 0..3 -> 64-col quarter
  // T1 XCD swizzle: contiguous row-tile chunk per XCD, col-tile fastest.
  const int wgid = (blockIdx.x & 7) * chunk + (blockIdx.x >> 3);
  const int row0 = (wgid >> 2) * 256;
  const int col0 = (wgid & 3) * 256;

  f32x4 acc[8][4] = {};

  const int lr = lane & 15;
  const int xrA = (lr & 7) << 4;          // A read-side XOR (row&7)<<4
  const int xrB = ((lr >> 1) & 3) << 4;   // B read-side XOR ((row>>1)&3)<<4
  const int ksA = (lane >> 4) * 32;       // A k-chunk byte base (8 fp32 = 32B)
  const int ksB = (lane >> 4) * 16;       // B k-chunk byte base (8 bf16 = 16B)

  // A staging: wave w, iter j covers rows w*8+j*64+(l>>3), slot l&7 (16B fp32
  // chunks); pre-swizzled source chunk = (l&7)^(l>>3) since row&7 == l>>3.
  const float* Ag = A + (long)(row0 + wid * 8 + (lane >> 3)) * DM +
                    (((lane & 7) ^ (lane >> 3)) << 2);
  // B staging: rows w*16+j*128+(l>>2), slot l&3; source chunk = (l&3)^((l>>3)&3).
  const bf16* Wg = W + (long)(col0 + wid * 16 + (lane >> 2)) * DM +
                   (((lane & 3) ^ ((lane >> 3) & 3)) << 3);

#define ISSUE_AB(ib, kt_) { \
  _Pragma("unroll") for (int j = 0; j < 4; ++j) \
    gload_lds16(Ag + (long)(j * 64) * DM + (kt_) * 32, \
                (void*)((char*)As[ib] + (wid * 8 + j * 64) * 128)); \
  _Pragma("unroll") for (int j = 0; j < 2; ++j) \
    gload_lds16(Wg + (long)(j * 128) * DM + (kt_) * 32, \
                (void*)((char*)Bs[ib] + (wid * 16 + j * 128) * 64)); }

#define TILE_BODY(buf) { \
  const char* AscB = (const char*)As[buf]; \
  const char* BscB = (const char*)Bs[buf]; \
  short8 af[4], bfv[4]; \
  _Pragma("unroll") for (int m = 0; m < 4; ++m) { \
    const int rb = (wr * 128 + m * 16 + lr) * 128; \
    f32x4 a0 = *(const f32x4*)(AscB + rb + (ksA ^ xrA)); \
    f32x4 a1 = *(const f32x4*)(AscB + rb + ((ksA + 16) ^ xrA)); \
    af[m] = cvt8(a0, a1); } \
  _Pragma("unroll") for (int n = 0; n < 4; ++n) \
    bfv[n] = *(const short8*)(BscB + (wc * 64 + n * 16 + lr) * 64 + (ksB ^ xrB)); \
  __builtin_amdgcn_sched_barrier(0); \
  __builtin_amdgcn_s_setprio(1); \
  _Pragma("unroll") for (int m = 0; m < 4; ++m) \
    _Pragma("unroll") for (int n = 0; n < 4; ++n) \
      acc[m][n] = __builtin_amdgcn_mfma_f32_16x16x32_bf16(af[m], bfv[n], acc[m][n], 0, 0, 0); \
  __builtin_amdgcn_s_setprio(0); \
  asm volatile("s_barrier" ::: "memory"); \
  _Pragma("unroll") for (int m = 0; m < 4; ++m) { \
    const int rb = (wr * 128 + (m + 4) * 16 + lr) * 128; \
    f32x4 a0 = *(const f32x4*)(AscB + rb + (ksA ^ xrA)); \
    f32x4 a1 = *(const f32x4*)(AscB + rb + ((ksA + 16) ^ xrA)); \
    af[m] = cvt8(a0, a1); } \
  asm volatile("s_barrier" ::: "memory"); \
  __builtin_amdgcn_sched_barrier(0); \
  __builtin_amdgcn_s_setprio(1); \
  _Pragma("unroll") for (int m = 0; m < 4; ++m) \
    _Pragma("unroll") for (int n = 0; n < 4; ++n) \
      acc[m + 4][n] = __builtin_amdgcn_mfma_f32_16x16x32_bf16(af[m], bfv[n], acc[m + 4][n], 0, 0, 0); \
  __builtin_amdgcn_s_setprio(0); \
  asm volatile("s_barrier" ::: "memory"); }

  // prologue: stage tiles 0,1 (12 loads in flight)
  ISSUE_AB(0, 0)
  ISSUE_AB(1, 1)

#pragma unroll 1
  for (int kt3 = 0; kt3 < 30; kt3 += 3) {
    ISSUE_AB(2, kt3 + 2)
    asm volatile("s_waitcnt vmcnt(12)\n\ts_barrier" ::: "memory");
    TILE_BODY(0)
    ISSUE_AB(0, kt3 + 3)
    asm volatile("s_waitcnt vmcnt(12)\n\ts_barrier" ::: "memory");
    TILE_BODY(1)
    ISSUE_AB(1, kt3 + 4)
    asm volatile("s_waitcnt vmcnt(12)\n\ts_barrier" ::: "memory");
    TILE_BODY(2)
  }
  // tiles 30 (buf0), 31 (buf1); in-flight {30,31}=12 at entry
  asm volatile("s_waitcnt vmcnt(6)\n\ts_barrier" ::: "memory");
  TILE_BODY(0)
  asm volatile("s_waitcnt vmcnt(0)\n\ts_barrier" ::: "memory");
  TILE_BODY(1)

#undef ISSUE_AB
#undef TILE_BODY

  // ---- epilogue: bias (+ elu+1 + Ksum), bf16, transposed store
  const int bglob = b0 + (row0 >> 12);
#pragma unroll
  for (int n = 0; n < 4; ++n) {
    const int colg = col0 + wc * 64 + n * 16 + lr;
    const float bv = bias[colg];
    float csum = 0.f;
#pragma unroll
    for (int m = 0; m < 8; ++m) {
      const int r = row0 + wr * 128 + m * 16 + (lane >> 4) * 4;
      union { ushort4 u; bf16 h[4]; } pk;
#pragma unroll
      for (int i = 0; i < 4; ++i) {
        float v = acc[m][n][i] + bv;
        if (KPROJ) { v = v > 0.f ? v + 1.f : __expf(v); csum += v; }
        pk.h[i] = __float2bfloat16(v);
      }
      *(ushort4*)&outT[(long)colg * rowsTot + r] = pk.u;
    }
    if (KPROJ) {
      csum += __shfl_xor(csum, 16);
      csum += __shfl_xor(csum, 32);
      if (lane < 16) atomicAdd(&Ksum[(long)bglob * DM + colg], csum);
    }
  }
}

// ---------------- KV partials: KVp[sp,b,h] = K^T @ V over s-range ----------
__global__ __launch_bounds__(256) void kv_kernel(
    const bf16* __restrict__ KT, const bf16* __restrict__ VT,
    float* __restrict__ KVp, int rowsTot, int b0) {
  const int sp = blockIdx.x & 3;
  const int h = (blockIdx.x >> 2) & 15;
  const int b_loc = blockIdx.x >> 6;
  const int lane = threadIdx.x & 63;
  const int w = threadIdx.x >> 6;
  const long srow = (long)b_loc * SEQ + sp * (SEQ / 4) + ((lane >> 4) * 8);
  const bf16* Ab = KT + (long)(h * DKH + w * 16 + (lane & 15)) * rowsTot + srow;
  const bf16* Bb = VT + (long)(h * DKH + (lane & 15)) * rowsTot + srow;
  f32x4 acc[4] = {};
#pragma unroll 4
  for (int s = 0; s < SEQ / 4; s += 32) {
    short8 a = *(const short8*)(Ab + s);
#pragma unroll
    for (int n = 0; n < 4; ++n) {
      short8 bv = *(const short8*)(Bb + (long)n * 16 * rowsTot + s);
      acc[n] = __builtin_amdgcn_mfma_f32_16x16x32_bf16(a, bv, acc[n], 0, 0, 0);
    }
  }
  float* o = KVp + (((long)sp * NB_B + (b0 + b_loc)) * NH + h) * DKH * DKH;
#pragma unroll
  for (int n = 0; n < 4; ++n)
#pragma unroll
    for (int i = 0; i < 4; ++i)
      o[(w * 16 + (lane >> 4) * 4 + i) * DKH + n * 16 + (lane & 15)] = acc[n][i];
}

// ---------------- small fp32 vec-mat ----------------
template <int ELU>
__global__ __launch_bounds__(256) void vecmat_kernel(
    const float* __restrict__ in, const float* __restrict__ W,
    const float* __restrict__ bias, float* __restrict__ outp) {
  const int b = blockIdx.x >> 5;
  const int n0 = (blockIdx.x & 31) * 32;
  const int lane = threadIdx.x & 63;
  const int w = threadIdx.x >> 6;
  float4 qv[4];
#pragma unroll
  for (int it = 0; it < 4; ++it)
    qv[it] = *(const float4*)&in[(long)b * DM + it * 256 + lane * 4];
#pragma unroll
  for (int j = 0; j < 8; ++j) {
    const int n = n0 + w * 8 + j;
    const float* wrow = W + (long)n * DM;
    float s = 0.f;
#pragma unroll
    for (int it = 0; it < 4; ++it) {
      float4 wv = *(const float4*)&wrow[it * 256 + lane * 4];
      s += qv[it].x * wv.x + qv[it].y * wv.y + qv[it].z * wv.z + qv[it].w * wv.w;
    }
    s += __shfl_xor(s, 1);  s += __shfl_xor(s, 2);  s += __shfl_xor(s, 4);
    s += __shfl_xor(s, 8);  s += __shfl_xor(s, 16); s += __shfl_xor(s, 32);
    if (lane == 0) {
      float v = s + bias[n];
      if (ELU) v = v > 0.f ? v + 1.f : __expf(v);
      outp[(long)b * DM + n] = v;
    }
  }
}

// ---- x = (Q . KV) * Z with KV = sum of 4 partials
__global__ __launch_bounds__(256) void xcomp_kernel(
    const float* __restrict__ Q, const float* __restrict__ KVp,
    const float* __restrict__ Ksum, float* __restrict__ xb) {
  const int b = blockIdx.x;
  const int t = threadIdx.x;
  const int h = t >> 4;
  const int m0 = (t & 15) * 4;
  const float* q = Q + (long)b * DM + h * DKH;
  const float* ks = Ksum + (long)b * DM + h * DKH;
  const long kvoff = ((long)b * NH + h) * DKH * DKH;
  const long spstride = (long)NB_B * NH * DKH * DKH;
  float zden = 0.f;
#pragma unroll
  for (int d = 0; d < DKH; ++d) zden += q[d] * ks[d];
  const float z = 1.f / (zden + 1e-6f);
  float nv[4] = {0.f, 0.f, 0.f, 0.f};
  for (int d = 0; d < DKH; ++d) {
    const float qd = q[d];
#pragma unroll
    for (int j = 0; j < 4; ++j) {
      const long idx = kvoff + d * DKH + m0 + j;
      nv[j] += qd * (KVp[idx] + KVp[idx + spstride] +
                     KVp[idx + 2 * spstride] + KVp[idx + 3 * spstride]);
    }
  }
  float* xo = xb + (long)b * DM + h * DKH + m0;
#pragma unroll
  for (int j = 0; j < 4; ++j) xo[j] = nv[j] * z;
}

extern "C" void kernel_launch(void* const* d_in, const int* in_sizes, int n_in,
                              void* d_out, int out_size, void* d_ws, size_t ws_size,
                              hipStream_t stream) {
  (void)in_sizes; (void)n_in; (void)out_size;
  const float* query = (const float*)d_in[0];
  const float* key   = (const float*)d_in[1];
  const float* value = (const float*)d_in[2];
  const float* Wq = (const float*)d_in[3];
  const float* bq = (const float*)d_in[4];
  const float* Wk = (const float*)d_in[5];
  const float* bk = (const float*)d_in[6];
  const float* Wv = (const float*)d_in[7];
  const float* bv = (const float*)d_in[8];
  const float* Wo = (const float*)d_in[9];
  const float* bo = (const float*)d_in[10];
  float* out = (float*)d_out;

  char* p = (char*)d_ws;
  bf16* WkB = (bf16*)p;  p += (size_t)DM * DM * 2;
  bf16* WvB = (bf16*)p;  p += (size_t)DM * DM * 2;
  float* KVp = (float*)p; p += (size_t)4 * NB_B * NH * DKH * DKH * 4;
  float* Ksum = (float*)p; p += (size_t)NB_B * DM * 4;
  float* Q = (float*)p;  p += (size_t)NB_B * DM * 4;
  float* xb = (float*)p; p += (size_t)NB_B * DM * 4;
  const size_t fixed = (size_t)(p - (char*)d_ws);
  const size_t per_b = (size_t)2 * SEQ * DM * 2;  // kT+vT per batch (bf16)
  if (ws_size < fixed + per_b) return;
  int nbc = (int)((ws_size - fixed) / per_b);
  if (nbc > NB_B) nbc = NB_B;
  bf16* kT = (bf16*)p; p += (size_t)nbc * SEQ * DM * 2;
  bf16* vT = (bf16*)p; p += (size_t)nbc * SEQ * DM * 2;

  hipMemsetAsync(Ksum, 0, (size_t)NB_B * DM * 4, stream);
  conv_kernel<<<512, 256, 0, stream>>>(Wk, WkB, (long)DM * DM / 4);
  conv_kernel<<<512, 256, 0, stream>>>(Wv, WvB, (long)DM * DM / 4);
  vecmat_kernel<1><<<NB_B * 32, 256, 0, stream>>>(query, Wq, bq, Q);

  for (int b0 = 0; b0 < NB_B; b0 += nbc) {
    const int nb = (NB_B - b0 < nbc) ? (NB_B - b0) : nbc;
    const int rows = nb * SEQ;
    const int nwg = (rows / 256) * 4;
    gemm256<1><<<nwg, 512, 0, stream>>>(key + (size_t)b0 * SEQ * DM, WkB, bk, kT, Ksum, rows, b0, nwg / 8);
    gemm256<0><<<nwg, 512, 0, stream>>>(value + (size_t)b0 * SEQ * DM, WvB, bv, vT, (float*)nullptr, rows, b0, nwg / 8);
    kv_kernel<<<nb * NH * 4, 256, 0, stream>>>(kT, vT, KVp, rows, b0);
  }

  xcomp_kernel<<<NB_B, 256, 0, stream>>>(Q, KVp, Ksum, xb);
  vecmat_kernel<0><<<NB_B * 32, 256, 0, stream>>>(xb, Wo, bo, out);
}

// Round 7
// 642.404 us; speedup vs baseline: 2.0267x; 1.0801x over previous
//
#include <hip/hip_runtime.h>
#include <hip/hip_bf16.h>
#include <stdint.h>

// LinearMultiHeadedAttention: B=16, S=4096, D=1024, H=16, DK=64
// R7: 256x256 8-wave GEMM. A = fp32 key/value direct (conv fused), staged
//     via global_load_lds into As[3][256][32] fp32 (128B rows, tri-buffered,
//     2 steps ahead). B = bf16 W in Bs[2][256][64] (128B rows, 1 tile ahead).
//     All LDS tiles 128B-row + 8-slot XOR swizzle (R4-verified, 0 conflicts).
//     Exact oldest-first vmcnt: issue {B2,A4}/step -> boundary vmcnt(4/6).
//     No sched_barrier pins (m141). 2 barriers per 16-MFMA phase + setprio.

using bf16 = __hip_bfloat16;
typedef __attribute__((ext_vector_type(8))) short short8;  // bf16x8 MFMA frag
typedef __attribute__((ext_vector_type(4))) float f32x4;

#define NB_B 16
#define SEQ 4096
#define DM 1024
#define NH 16
#define DKH 64

__device__ __forceinline__ void gload_lds16(const void* g, void* l) {
  __builtin_amdgcn_global_load_lds((const __attribute__((address_space(1))) void*)g,
                                   (__attribute__((address_space(3))) void*)l, 16, 0, 0);
}

__device__ __forceinline__ short8 cvt8(f32x4 a, f32x4 b) {
  union { bf16 h[8]; short8 v; } pk;
  pk.h[0] = __float2bfloat16(a[0]); pk.h[1] = __float2bfloat16(a[1]);
  pk.h[2] = __float2bfloat16(a[2]); pk.h[3] = __float2bfloat16(a[3]);
  pk.h[4] = __float2bfloat16(b[0]); pk.h[5] = __float2bfloat16(b[1]);
  pk.h[6] = __float2bfloat16(b[2]); pk.h[7] = __float2bfloat16(b[3]);
  return pk.v;
}

// ---------------- fp32 -> bf16 conversion (weights only) ----------------
__global__ __launch_bounds__(256) void conv_kernel(const float* __restrict__ src,
                                                   bf16* __restrict__ dst, long n4) {
  long i = (long)blockIdx.x * blockDim.x + threadIdx.x;
  const long stride = (long)gridDim.x * blockDim.x;
  for (; i < n4; i += stride) {
    float4 v = ((const float4*)src)[i];
    union { ushort4 u; bf16 h[4]; } o;
    o.h[0] = __float2bfloat16(v.x);
    o.h[1] = __float2bfloat16(v.y);
    o.h[2] = __float2bfloat16(v.z);
    o.h[3] = __float2bfloat16(v.w);
    ((ushort4*)dst)[i] = o.u;
  }
}

// ---------------- 256x256 8-wave deep-pipelined projection GEMM ------------
// C[row][col] = sum_c A[row][c] * W[col][c]  (+bias[col]); KPROJ: elu+1, Ksum.
// A: fp32 [rowsTot][DM]. W: bf16 [DM][DM]. Out TRANSPOSED bf16 outT[col][row].
// 32 half-steps of K=32. Per step: 2 phases x {reads, 16 MFMA}, 2 barriers.
template <int KPROJ>
__global__ __launch_bounds__(512, 2) void gemm256(
    const float* __restrict__ A, const bf16* __restrict__ W,
    const float* __restrict__ bias, bf16* __restrict__ outT,
    float* __restrict__ Ksum, int rowsTot, int b0, int chunk) {
  __shared__ float As[3][256 * 32];  // 96 KiB, 128B rows
  __shared__ bf16 Bs[2][256 * 64];   // 64 KiB, 128B rows
  const int tid = threadIdx.x;
  const int lane = tid & 63;
  const int wid = tid >> 6;   // 0..7
  const int wr = wid >> 2;    // 0..1 -> 128-row half
  const int wc = wid & 3;     // 0..3 -> 64-col quarter
  // T1 XCD swizzle: contiguous row-tile chunk per XCD, col-tile fastest.
  const int wgid = (blockIdx.x & 7) * chunk + (blockIdx.x >> 3);
  const int row0 = (wgid >> 2) * 256;
  const int col0 = (wgid & 3) * 256;

  f32x4 acc[8][4] = {};

  const int lr = lane & 15;
  const int xr = (lr & 7) << 4;      // read-side XOR key (row&7 == lr&7)
  const int g32 = (lane >> 4) * 32;  // A k-chunk byte base (slot 2g)
  const int g16 = (lane >> 4) * 16;  // B k-chunk byte base

  // staging: wave w, instr j covers rows w*8 + j*64 + (l>>3);
  // pre-swizzled source slot (l&7)^(l>>3) since dest slot l&7, row&7 = l>>3.
  const float* Ag = A + (long)(row0 + wid * 8 + (lane >> 3)) * DM +
                    (((lane & 7) ^ (lane >> 3)) << 2);
  const bf16* Wg = W + (long)(col0 + wid * 8 + (lane >> 3)) * DM +
                   (((lane & 7) ^ (lane >> 3)) << 3);

#define SA_ONE(dstbuf, j, H_) \
  gload_lds16(Ag + (long)((j) * 64) * DM + (H_) * 32, \
              (void*)&As[dstbuf][(wid * 8 + (j) * 64) * 32]);
#define SB_ONE(dstbuf, j, T_) \
  gload_lds16(Wg + (long)((j) * 64) * DM + (T_) * 64, \
              (void*)&Bs[dstbuf][(wid * 8 + (j) * 64) * 64]);

// One K=32 half-step. H runtime step index; AB/BB/HALF/SA/SB literals; VMS string.
#define STEP(H, AB, BB, HALF, SA, SB, VMS) { \
    asm volatile("s_waitcnt vmcnt(" VMS ")\n\ts_barrier" ::: "memory"); \
    if (SB) { SB_ONE((BB) ^ 1, 2 * (HALF), ((H) >> 1) + 1) \
              SB_ONE((BB) ^ 1, 2 * (HALF) + 1, ((H) >> 1) + 1) } \
    const char* AsB = (const char*)As[(AB)]; \
    const char* BsB = (const char*)Bs[(BB)]; \
    short8 af[4], bfv[4]; \
    _Pragma("unroll") for (int m = 0; m < 4; ++m) { \
      const int rb = (wr * 128 + m * 16 + lr) * 128; \
      f32x4 a0 = *(const f32x4*)(AsB + rb + (g32 ^ xr)); \
      f32x4 a1 = *(const f32x4*)(AsB + rb + ((g32 + 16) ^ xr)); \
      af[m] = cvt8(a0, a1); } \
    _Pragma("unroll") for (int n = 0; n < 4; ++n) \
      bfv[n] = *(const short8*)(BsB + (wc * 64 + n * 16 + lr) * 128 + \
                                (((HALF) * 64 + g16) ^ xr)); \
    __builtin_amdgcn_s_setprio(1); \
    _Pragma("unroll") for (int m = 0; m < 4; ++m) \
      _Pragma("unroll") for (int n = 0; n < 4; ++n) \
        acc[m][n] = __builtin_amdgcn_mfma_f32_16x16x32_bf16(af[m], bfv[n], acc[m][n], 0, 0, 0); \
    __builtin_amdgcn_s_setprio(0); \
    asm volatile("s_barrier" ::: "memory"); \
    if (SA) { _Pragma("unroll") for (int j = 0; j < 4; ++j) \
                SA_ONE(((AB) + 2) % 3, j, (H) + 2) } \
    _Pragma("unroll") for (int m = 0; m < 4; ++m) { \
      const int rb = (wr * 128 + (m + 4) * 16 + lr) * 128; \
      f32x4 a0 = *(const f32x4*)(AsB + rb + (g32 ^ xr)); \
      f32x4 a1 = *(const f32x4*)(AsB + rb + ((g32 + 16) ^ xr)); \
      af[m] = cvt8(a0, a1); } \
    __builtin_amdgcn_s_setprio(1); \
    _Pragma("unroll") for (int m = 0; m < 4; ++m) \
      _Pragma("unroll") for (int n = 0; n < 4; ++n) \
        acc[m + 4][n] = __builtin_amdgcn_mfma_f32_16x16x32_bf16(af[m], bfv[n], acc[m + 4][n], 0, 0, 0); \
    __builtin_amdgcn_s_setprio(0); \
  }

  // ---- prologue (issue order = steady-state ages): B(0)h1, A(0), B(0)h2, A(1)
  SB_ONE(0, 0, 0) SB_ONE(0, 1, 0)
#pragma unroll
  for (int j = 0; j < 4; ++j) SA_ONE(0, j, 0)
  SB_ONE(0, 2, 0) SB_ONE(0, 3, 0)
#pragma unroll
  for (int j = 0; j < 4; ++j) SA_ONE(1, j, 1)

  // ---- main loop: steps 0..23 (12-step period -> all indices literal)
#pragma unroll 1
  for (int hb = 0; hb < 24; hb += 12) {
    STEP(hb + 0, 0, 0, 0, 1, 1, "4")
    STEP(hb + 1, 1, 0, 1, 1, 1, "6")
    STEP(hb + 2, 2, 1, 0, 1, 1, "4")
    STEP(hb + 3, 0, 1, 1, 1, 1, "6")
    STEP(hb + 4, 1, 0, 0, 1, 1, "4")
    STEP(hb + 5, 2, 0, 1, 1, 1, "6")
    STEP(hb + 6, 0, 1, 0, 1, 1, "4")
    STEP(hb + 7, 1, 1, 1, 1, 1, "6")
    STEP(hb + 8, 2, 0, 0, 1, 1, "4")
    STEP(hb + 9, 0, 0, 1, 1, 1, "6")
    STEP(hb + 10, 1, 1, 0, 1, 1, "4")
    STEP(hb + 11, 2, 1, 1, 1, 1, "6")
  }
  // ---- tail: steps 24..31 (stage only while h <= 29)
  STEP(24, 0, 0, 0, 1, 1, "4")
  STEP(25, 1, 0, 1, 1, 1, "6")
  STEP(26, 2, 1, 0, 1, 1, "4")
  STEP(27, 0, 1, 1, 1, 1, "6")
  STEP(28, 1, 0, 0, 1, 1, "4")
  STEP(29, 2, 0, 1, 1, 1, "6")
  STEP(30, 0, 1, 0, 0, 0, "4")
  STEP(31, 1, 1, 1, 0, 0, "0")

#undef STEP
#undef SA_ONE
#undef SB_ONE

  // ---- epilogue: bias (+ elu+1 + Ksum), bf16, transposed store
  const int bglob = b0 + (row0 >> 12);
#pragma unroll
  for (int n = 0; n < 4; ++n) {
    const int colg = col0 + wc * 64 + n * 16 + lr;
    const float bv = bias[colg];
    float csum = 0.f;
#pragma unroll
    for (int m = 0; m < 8; ++m) {
      const int r = row0 + wr * 128 + m * 16 + (lane >> 4) * 4;
      union { ushort4 u; bf16 h[4]; } pk;
#pragma unroll
      for (int i = 0; i < 4; ++i) {
        float v = acc[m][n][i] + bv;
        if (KPROJ) { v = v > 0.f ? v + 1.f : __expf(v); csum += v; }
        pk.h[i] = __float2bfloat16(v);
      }
      *(ushort4*)&outT[(long)colg * rowsTot + r] = pk.u;
    }
    if (KPROJ) {
      csum += __shfl_xor(csum, 16);
      csum += __shfl_xor(csum, 32);
      if (lane < 16) atomicAdd(&Ksum[(long)bglob * DM + colg], csum);
    }
  }
}

// ---------------- KV partials: KVp[sp,b,h] = K^T @ V over s-range ----------
__global__ __launch_bounds__(256) void kv_kernel(
    const bf16* __restrict__ KT, const bf16* __restrict__ VT,
    float* __restrict__ KVp, int rowsTot, int b0) {
  const int sp = blockIdx.x & 3;
  const int h = (blockIdx.x >> 2) & 15;
  const int b_loc = blockIdx.x >> 6;
  const int lane = threadIdx.x & 63;
  const int w = threadIdx.x >> 6;
  const long srow = (long)b_loc * SEQ + sp * (SEQ / 4) + ((lane >> 4) * 8);
  const bf16* Ab = KT + (long)(h * DKH + w * 16 + (lane & 15)) * rowsTot + srow;
  const bf16* Bb = VT + (long)(h * DKH + (lane & 15)) * rowsTot + srow;
  f32x4 acc[4] = {};
#pragma unroll 4
  for (int s = 0; s < SEQ / 4; s += 32) {
    short8 a = *(const short8*)(Ab + s);
#pragma unroll
    for (int n = 0; n < 4; ++n) {
      short8 bv = *(const short8*)(Bb + (long)n * 16 * rowsTot + s);
      acc[n] = __builtin_amdgcn_mfma_f32_16x16x32_bf16(a, bv, acc[n], 0, 0, 0);
    }
  }
  float* o = KVp + (((long)sp * NB_B + (b0 + b_loc)) * NH + h) * DKH * DKH;
#pragma unroll
  for (int n = 0; n < 4; ++n)
#pragma unroll
    for (int i = 0; i < 4; ++i)
      o[(w * 16 + (lane >> 4) * 4 + i) * DKH + n * 16 + (lane & 15)] = acc[n][i];
}

// ---------------- small fp32 vec-mat ----------------
template <int ELU>
__global__ __launch_bounds__(256) void vecmat_kernel(
    const float* __restrict__ in, const float* __restrict__ W,
    const float* __restrict__ bias, float* __restrict__ outp) {
  const int b = blockIdx.x >> 5;
  const int n0 = (blockIdx.x & 31) * 32;
  const int lane = threadIdx.x & 63;
  const int w = threadIdx.x >> 6;
  float4 qv[4];
#pragma unroll
  for (int it = 0; it < 4; ++it)
    qv[it] = *(const float4*)&in[(long)b * DM + it * 256 + lane * 4];
#pragma unroll
  for (int j = 0; j < 8; ++j) {
    const int n = n0 + w * 8 + j;
    const float* wrow = W + (long)n * DM;
    float s = 0.f;
#pragma unroll
    for (int it = 0; it < 4; ++it) {
      float4 wv = *(const float4*)&wrow[it * 256 + lane * 4];
      s += qv[it].x * wv.x + qv[it].y * wv.y + qv[it].z * wv.z + qv[it].w * wv.w;
    }
    s += __shfl_xor(s, 1);  s += __shfl_xor(s, 2);  s += __shfl_xor(s, 4);
    s += __shfl_xor(s, 8);  s += __shfl_xor(s, 16); s += __shfl_xor(s, 32);
    if (lane == 0) {
      float v = s + bias[n];
      if (ELU) v = v > 0.f ? v + 1.f : __expf(v);
      outp[(long)b * DM + n] = v;
    }
  }
}

// ---- x = (Q . KV) * Z with KV = sum of 4 partials
__global__ __launch_bounds__(256) void xcomp_kernel(
    const float* __restrict__ Q, const float* __restrict__ KVp,
    const float* __restrict__ Ksum, float* __restrict__ xb) {
  const int b = blockIdx.x;
  const int t = threadIdx.x;
  const int h = t >> 4;
  const int m0 = (t & 15) * 4;
  const float* q = Q + (long)b * DM + h * DKH;
  const float* ks = Ksum + (long)b * DM + h * DKH;
  const long kvoff = ((long)b * NH + h) * DKH * DKH;
  const long spstride = (long)NB_B * NH * DKH * DKH;
  float zden = 0.f;
#pragma unroll
  for (int d = 0; d < DKH; ++d) zden += q[d] * ks[d];
  const float z = 1.f / (zden + 1e-6f);
  float nv[4] = {0.f, 0.f, 0.f, 0.f};
  for (int d = 0; d < DKH; ++d) {
    const float qd = q[d];
#pragma unroll
    for (int j = 0; j < 4; ++j) {
      const long idx = kvoff + d * DKH + m0 + j;
      nv[j] += qd * (KVp[idx] + KVp[idx + spstride] +
                     KVp[idx + 2 * spstride] + KVp[idx + 3 * spstride]);
    }
  }
  float* xo = xb + (long)b * DM + h * DKH + m0;
#pragma unroll
  for (int j = 0; j < 4; ++j) xo[j] = nv[j] * z;
}

extern "C" void kernel_launch(void* const* d_in, const int* in_sizes, int n_in,
                              void* d_out, int out_size, void* d_ws, size_t ws_size,
                              hipStream_t stream) {
  (void)in_sizes; (void)n_in; (void)out_size;
  const float* query = (const float*)d_in[0];
  const float* key   = (const float*)d_in[1];
  const float* value = (const float*)d_in[2];
  const float* Wq = (const float*)d_in[3];
  const float* bq = (const float*)d_in[4];
  const float* Wk = (const float*)d_in[5];
  const float* bk = (const float*)d_in[6];
  const float* Wv = (const float*)d_in[7];
  const float* bv = (const float*)d_in[8];
  const float* Wo = (const float*)d_in[9];
  const float* bo = (const float*)d_in[10];
  float* out = (float*)d_out;

  char* p = (char*)d_ws;
  bf16* WkB = (bf16*)p;  p += (size_t)DM * DM * 2;
  bf16* WvB = (bf16*)p;  p += (size_t)DM * DM * 2;
  float* KVp = (float*)p; p += (size_t)4 * NB_B * NH * DKH * DKH * 4;
  float* Ksum = (float*)p; p += (size_t)NB_B * DM * 4;
  float* Q = (float*)p;  p += (size_t)NB_B * DM * 4;
  float* xb = (float*)p; p += (size_t)NB_B * DM * 4;
  const size_t fixed = (size_t)(p - (char*)d_ws);
  const size_t per_b = (size_t)2 * SEQ * DM * 2;  // kT+vT per batch (bf16)
  if (ws_size < fixed + per_b) return;
  int nbc = (int)((ws_size - fixed) / per_b);
  if (nbc > NB_B) nbc = NB_B;
  bf16* kT = (bf16*)p; p += (size_t)nbc * SEQ * DM * 2;
  bf16* vT = (bf16*)p; p += (size_t)nbc * SEQ * DM * 2;

  hipMemsetAsync(Ksum, 0, (size_t)NB_B * DM * 4, stream);
  conv_kernel<<<512, 256, 0, stream>>>(Wk, WkB, (long)DM * DM / 4);
  conv_kernel<<<512, 256, 0, stream>>>(Wv, WvB, (long)DM * DM / 4);
  vecmat_kernel<1><<<NB_B * 32, 256, 0, stream>>>(query, Wq, bq, Q);

  for (int b0 = 0; b0 < NB_B; b0 += nbc) {
    const int nb = (NB_B - b0 < nbc) ? (NB_B - b0) : nbc;
    const int rows = nb * SEQ;
    const int nwg = (rows / 256) * 4;
    gemm256<1><<<nwg, 512, 0, stream>>>(key + (size_t)b0 * SEQ * DM, WkB, bk, kT, Ksum, rows, b0, nwg / 8);
    gemm256<0><<<nwg, 512, 0, stream>>>(value + (size_t)b0 * SEQ * DM, WvB, bv, vT, (float*)nullptr, rows, b0, nwg / 8);
    kv_kernel<<<nb * NH * 4, 256, 0, stream>>>(kT, vT, KVp, rows, b0);
  }

  xcomp_kernel<<<NB_B, 256, 0, stream>>>(Q, KVp, Ksum, xb);
  vecmat_kernel<0><<<NB_B * 32, 256, 0, stream>>>(xb, Wo, bo, out);
}